// Round 14
// baseline (421.792 us; speedup 1.0000x reference)
//
#include <hip/hip_runtime.h>
#include <hip/hip_bf16.h>
#include <stdint.h>

#define LL 1024
#define CC 128
#define NG 8            // B*S graphs
#define NN (NG*LL)      // 8192 nodes total
typedef __hip_bfloat16 bf16;
typedef __attribute__((ext_vector_type(8))) short short8;
typedef __attribute__((ext_vector_type(4))) short short4v;
typedef __attribute__((ext_vector_type(4))) float f32x4;

__device__ __forceinline__ bool is_bf16_wire(const void* gamma) {
  return *(const uint32_t*)gamma == 0x3F803F80u;
}
__device__ __forceinline__ float ldw(const void* p, size_t i, bool bf) {
  return bf ? __bfloat162float(((const bf16*)p)[i]) : ((const float*)p)[i];
}
__device__ __forceinline__ uint32_t encf(float f) {
  uint32_t b = __float_as_uint(f);
  return (b & 0x80000000u) ? ~b : (b | 0x80000000u);
}
__device__ __forceinline__ float decf(uint32_t u) {
  return (u & 0x80000000u) ? __uint_as_float(u & 0x7FFFFFFFu) : __uint_as_float(~u);
}
__device__ __forceinline__ short f2bs(float x) {   // RNE, matches cvt_pk_bf16
  uint32_t u = __float_as_uint(x);
  u += 0x7FFFu + ((u >> 16) & 1u);
  return (short)(u >> 16);
}
__device__ __forceinline__ void cvt8(const void* src, bf16* dst, int i8, bool bf) {
  if (bf) {
    ((uint4*)dst)[i8] = ((const uint4*)src)[i8];
  } else {
    const float4* f = (const float4*)src;
    float4 a = f[2 * i8], b = f[2 * i8 + 1];
    short8 pk;
    pk[0] = f2bs(a.x); pk[1] = f2bs(a.y); pk[2] = f2bs(a.z); pk[3] = f2bs(a.w);
    pk[4] = f2bs(b.x); pk[5] = f2bs(b.y); pk[6] = f2bs(b.z); pk[7] = f2bs(b.w);
    *(short8*)&((short*)dst)[i8 * 8] = pk;
  }
}

// WfTf fragment-native layout: elem(g,n,o) = g*131072 + (n>>2)*512 + o*4 + (n&3)

// ---------------- k_front: convert (blocks 0-511) + adj LDS-bitmask (512-575)
// r14: adjacency built per (graph, 128-row band) in a 16 KB LDS bitmask via
// ds-atomicOr, written out once coalesced. Kills the 137 MB HBM writeback of
// the byte-scatter (r13 counters), the 8 MB adj buffer+memset, and the pack.
__global__ __launch_bounds__(256) void k_front(
    const void* __restrict__ feats, const void* __restrict__ W1,
    const void* __restrict__ W2, const void* __restrict__ as1,
    const void* __restrict__ ad1, const void* __restrict__ as2,
    const void* __restrict__ ad2, const void* __restrict__ gamma,
    bf16* __restrict__ xb, bf16* __restrict__ Wb1, bf16* __restrict__ Wb2,
    bf16* __restrict__ sm, const int* __restrict__ img,
    uint32_t* __restrict__ bits) {
  __shared__ uint32_t lb[4096];                  // 128 rows x 32 words = 16 KB
  int bid = blockIdx.x;
  if (bid < 512) {
    const bool bf = is_bf16_wire(gamma);
    int t = bid * 256 + threadIdx.x;             // < 131072
    cvt8(feats, xb, t, bf);
    if (t < 2048) {
      cvt8(W1, Wb1, t, bf);
    } else if (t < 4096) {
      cvt8(W2, Wb2, t - 2048, bf);
    } else if (t < 4160) {
      int j = t - 4096;
      const void* srcs[4] = {as1, ad1, as2, ad2};
      cvt8(srcs[j >> 4], sm + (j >> 4) * 128, j & 15, bf);
    }
  } else {
    int wg = bid - 512;                          // 0..63
    int g = wg >> 3, r0 = (wg & 7) * 128;        // graph, row band [r0, r0+128)
    int t = threadIdx.x;
    for (int u = t; u < 4096; u += 256) lb[u] = 0;
    __syncthreads();
    const int* im = img + g * 65536;
    for (int k = 0; k < 256; k++) {
      int p = k * 256 + t;                       // coalesced scan
      int y = p >> 8, x = p & 255;
      int a = im[p];
      if (a > 0) {
        int nxs[4] = {x + 1, x, x + 1, x - 1};
        int nys[4] = {y, y + 1, y + 1, y + 1};
#pragma unroll
        for (int d = 0; d < 4; d++) {
          int nx = nxs[d], ny = nys[d];
          if (nx < 0 || nx > 255 || ny > 255) continue;
          int b = im[ny * 256 + nx];
          if (b > 0 && b != a) {
            int ra = a - 1, rb = b - 1;
            if (ra >= r0 && ra < r0 + 128)
              atomicOr(&lb[(ra - r0) * 32 + (rb >> 5)], 1u << (rb & 31));
            if (rb >= r0 && rb < r0 + 128)
              atomicOr(&lb[(rb - r0) * 32 + (ra >> 5)], 1u << (ra & 31));
          }
        }
      }
    }
    __syncthreads();
    uint32_t* dst = bits + g * 32768 + r0 * 32;
    for (int u = t; u < 4096; u += 256) {
      int r = u >> 5, wd = u & 31;
      uint32_t v = lb[u];
      int i = r0 + r;
      if ((i >> 5) == wd) v |= 1u << (i & 31);   // self-loop diagonal
      dst[u] = v;
    }
  }
}

// ---------------- shared MFMA-GEMM core (per-wave; 16 nodes x 128 o x 128 k)
template <int NH>
__device__ __forceinline__ void gemm_core(const short8 af[4],
    const bf16* __restrict__ Wb, const bf16* __restrict__ asb,
    const bf16* __restrict__ adb, bf16* __restrict__ WfT,
    float* __restrict__ es, float* __restrict__ ed,
    uint32_t* __restrict__ edmax, int n0, int lane) {
  int quad = lane >> 4, c = lane & 15;
  int g = n0 >> 10;
  f32x4 acc[8];
#pragma unroll
  for (int dt = 0; dt < 8; dt++) acc[dt] = (f32x4){0.f, 0.f, 0.f, 0.f};
#pragma unroll
  for (int ks = 0; ks < 4; ks++)
#pragma unroll
    for (int dt = 0; dt < 8; dt++) {
      short8 bfr = *(const short8*)&Wb[(size_t)(dt * 16 + c) * CC + ks * 32 + quad * 8];
      acc[dt] = __builtin_amdgcn_mfma_f32_16x16x32_bf16(af[ks], bfr, acc[dt], 0, 0, 0);
    }
  // WfTf store: nw4 = nloc/4 + quad, o = dt*16+c -> coalesced 8B chunks
  {
    int nw4 = ((n0 & 1023) >> 2) + quad;
    bf16* wdst = WfT + (size_t)g * 131072 + (size_t)nw4 * 512 + c * 4;
#pragma unroll
    for (int dt = 0; dt < 8; dt++) {
      short4v pk;
#pragma unroll
      for (int r = 0; r < 4; r++) pk[r] = f2bs(acc[dt][r]);
      *(short4v*)&wdst[dt * 64] = pk;
    }
  }
  float sv[NH][4], dv[NH][4];
#pragma unroll
  for (int h = 0; h < NH; h++)
#pragma unroll
    for (int r = 0; r < 4; r++) { sv[h][r] = 0.f; dv[h][r] = 0.f; }
#pragma unroll
  for (int dt = 0; dt < 8; dt++) {
    int o = dt * 16 + c;
    float a_s = __bfloat162float(asb[o]);
    float a_d = __bfloat162float(adb[o]);
    int h = (NH == 4) ? (dt >> 1) : 0;
#pragma unroll
    for (int r = 0; r < 4; r++) {
      sv[h][r] += acc[dt][r] * a_s;
      dv[h][r] += acc[dt][r] * a_d;
    }
  }
#pragma unroll
  for (int m = 1; m <= 8; m <<= 1)
#pragma unroll
    for (int h = 0; h < NH; h++)
#pragma unroll
      for (int r = 0; r < 4; r++) {
        sv[h][r] += __shfl_xor(sv[h][r], m);
        dv[h][r] += __shfl_xor(dv[h][r], m);
      }
  if (c == 0) {
#pragma unroll
    for (int r = 0; r < 4; r++) {
      int node = n0 + quad * 4 + r;
#pragma unroll
      for (int h = 0; h < NH; h++) {
        es[node * NH + h] = sv[h][r];
        ed[node * NH + h] = dv[h][r];
      }
    }
  }
  float mq[NH];
#pragma unroll
  for (int h = 0; h < NH; h++) {
    mq[h] = fmaxf(fmaxf(dv[h][0], dv[h][1]), fmaxf(dv[h][2], dv[h][3]));
    mq[h] = fmaxf(mq[h], __shfl_xor(mq[h], 16));
    mq[h] = fmaxf(mq[h], __shfl_xor(mq[h], 32));
  }
  if (lane == 0)
#pragma unroll
    for (int h = 0; h < NH; h++)
      atomicMax(&edmax[g * NH + h], encf(mq[h]));
}

// ---------------- k_gemm1: MFMA GEMM layer 1 (grid 128, 4 waves x 16 nodes) -
__global__ __launch_bounds__(256) void k_gemm1(
    const bf16* __restrict__ xb, const bf16* __restrict__ Wb1,
    const bf16* __restrict__ sm, bf16* __restrict__ WfT,
    float* __restrict__ es, float* __restrict__ ed,
    uint32_t* __restrict__ edmax) {
  int t = threadIdx.x;
  int lane = t & 63, w = t >> 6;
  int quad = lane >> 4, c = lane & 15;
  int n0 = blockIdx.x * 64 + w * 16;
  short8 af[4];
#pragma unroll
  for (int ks = 0; ks < 4; ks++)
    af[ks] = *(const short8*)&xb[(size_t)(n0 + c) * CC + ks * 32 + quad * 8];
  gemm_core<4>(af, Wb1, sm, sm + 128, WfT, es, ed, edmax, n0, lane);
}

// ---------------- MFMA GAT aggregation: 16-row blocks, j-split waves --------
// grid 1024 = g(8) x rowtile(64: 16 rows) x jp(2: 512 j).
template <int NH>
__global__ __launch_bounds__(256) void k_attn(
    const bf16* __restrict__ WfT, const float* __restrict__ esb,
    const float* __restrict__ edb, const uint32_t* __restrict__ bits,
    const uint32_t* __restrict__ edmax, bf16* __restrict__ pacc,
    float* __restrict__ pml) {
  __shared__ __align__(16) float red[4224];      // 2 wave-accs / ob buffer
  __shared__ float eds[NH * 520];                // ed transposed [h][j-local]
  __shared__ float lred[4][16 * NH];
  int t = threadIdx.x;
  int lane = t & 63, w = t >> 6;
  int quad = lane >> 4, c = lane & 15;
  int bid = blockIdx.x;
  int jp = bid & 1, rt = (bid >> 1) & 63, g = bid >> 7;
  int i0 = rt * 16;
  int node = g * LL + i0 + c;
  int J0 = jp * 512 + w * 128;                   // wave's j base within graph
  for (int u = t; u < 512 * NH; u += 256) {
    int h = u >> 9, j = u & 511;
    eds[h * 520 + j] = edb[(size_t)(g * LL + jp * 512 + j) * NH + h];
  }
  const float LOG2E = 1.44269504f;
  float esv[NH], cmv[NH];
  if (NH == 4) {
    const float4 e4 = *(const float4*)&esb[(size_t)node * 4];
    esv[0] = e4.x; esv[1] = e4.y; esv[2] = e4.z; esv[3] = e4.w;
  } else {
    esv[0] = esb[node];
  }
#pragma unroll
  for (int h = 0; h < NH; h++) {
    float mx = decf(edmax[NH == 4 ? g * 4 + h : g]);
    float m = esv[h] + mx; m = fmaxf(m, 0.2f * m);   // safe row-max upper bound
    cmv[h] = -m * LOG2E;
  }
  uint4 mk = *(const uint4*)&bits[(size_t)node * 32 + jp * 16 + w * 4];
  const uint32_t mkw[4] = {mk.x, mk.y, mk.z, mk.w};
  f32x4 acc[8];
#pragma unroll
  for (int dt = 0; dt < 8; dt++) acc[dt] = (f32x4){0.f, 0.f, 0.f, 0.f};
  float lsum[NH];
#pragma unroll
  for (int h = 0; h < NH; h++) lsum[h] = 0.f;
  const bf16* wb = WfT + (size_t)g * 131072 + (size_t)J0 * 128 + quad * 1024 + c * 4;
  __syncthreads();

  union FB { uint2 u[2]; short8 s; };
#pragma unroll
  for (int jb = 0; jb < 4; jb++) {
    short8 frag[8];
#pragma unroll
    for (int dt = 0; dt < 8; dt++) {
      FB f;
      f.u[0] = *(const uint2*)&wb[jb * 4096 + dt * 64];
      f.u[1] = *(const uint2*)&wb[jb * 4096 + dt * 64 + 512];
      frag[dt] = f.s;
    }
    int base_wj = w * 128 + jb * 32 + quad * 8;  // local j within block window
    uint32_t mw = mkw[jb] >> (quad * 8);
    float mf[8];
#pragma unroll
    for (int i = 0; i < 8; i++) mf[i] = (float)((mw >> i) & 1u);
#pragma unroll
    for (int h = 0; h < NH; h++) {
      const float* ep = &eds[h * 520 + base_wj];
      float4 ea = *(const float4*)ep;
      float4 eb = *(const float4*)(ep + 4);
      float ev[8] = {ea.x, ea.y, ea.z, ea.w, eb.x, eb.y, eb.z, eb.w};
      float pr[8];
      float lac = 0.f;
#pragma unroll
      for (int i = 0; i < 8; i++) {
        float e = esv[h] + ev[i];
        e = fmaxf(e, 0.2f * e);                  // leaky_relu
        float p = exp2f(fmaf(e, LOG2E, cmv[h]));
        p *= mf[i];
        lac += p;
        pr[i] = p;
      }
      lsum[h] += lac;
      union { short8 s; uint32_t u[4]; } A;
#pragma unroll
      for (int k = 0; k < 4; k++) {
        __hip_bfloat162 q = __float22bfloat162_rn(make_float2(pr[2*k], pr[2*k+1]));
        A.u[k] = *reinterpret_cast<uint32_t*>(&q);
      }
#pragma unroll
      for (int d2 = 0; d2 < 8 / NH; d2++) {
        int dt = h * (8 / NH) + d2;
        acc[dt] = __builtin_amdgcn_mfma_f32_16x16x32_bf16(A.s, frag[dt], acc[dt], 0, 0, 0);
      }
    }
  }
  // l: quad-reduce, stash per-wave row sums
#pragma unroll
  for (int h = 0; h < NH; h++) {
    float v = lsum[h];
    v += __shfl_xor(v, 16);
    v += __shfl_xor(v, 32);
    lsum[h] = v;
  }
  if (quad == 0)
#pragma unroll
    for (int h = 0; h < NH; h++) lred[w][c * NH + h] = lsum[h];
  // ---- cross-wave acc reduction (f32, float4 conflict-free) ----
  if (w == 1)
#pragma unroll
    for (int dt = 0; dt < 8; dt++) *(f32x4*)&red[dt * 256 + lane * 4] = acc[dt];
  if (w == 3)
#pragma unroll
    for (int dt = 0; dt < 8; dt++) *(f32x4*)&red[2048 + dt * 256 + lane * 4] = acc[dt];
  __syncthreads();
  if (w == 0)
#pragma unroll
    for (int dt = 0; dt < 8; dt++) acc[dt] += *(const f32x4*)&red[dt * 256 + lane * 4];
  if (w == 2)
#pragma unroll
    for (int dt = 0; dt < 8; dt++) acc[dt] += *(const f32x4*)&red[2048 + dt * 256 + lane * 4];
  __syncthreads();
  if (w == 2)
#pragma unroll
    for (int dt = 0; dt < 8; dt++) *(f32x4*)&red[dt * 256 + lane * 4] = acc[dt];
  __syncthreads();
  if (w == 0) {
#pragma unroll
    for (int dt = 0; dt < 8; dt++) acc[dt] += *(const f32x4*)&red[dt * 256 + lane * 4];
    // write reduced block tile to ob region: [row][d] stride 132 (2-way free)
#pragma unroll
    for (int dt = 0; dt < 8; dt++)
#pragma unroll
      for (int r = 0; r < 4; r++)
        red[2048 + (quad * 4 + r) * 132 + dt * 16 + c] = acc[dt][r];
  }
  __syncthreads();
  // cooperative coalesced partial store (16 rows x 128 d bf16 = 4 KB/block)
  {
    int row = t >> 4, d0 = (t & 15) * 8;
    const float* src = &red[2048 + row * 132 + d0];
    short8 pk;
#pragma unroll
    for (int k = 0; k < 8; k++) pk[k] = f2bs(src[k]);
    *(short8*)&pacc[((size_t)jp * NN + g * LL + i0 + row) * CC + d0] = pk;
  }
  if (t < 16 * NH) {
    float l = lred[0][t] + lred[1][t] + lred[2][t] + lred[3][t];
    int row = (NH == 4) ? (t >> 2) : t;
    int h = (NH == 4) ? (t & 3) : 0;
    if (NH == 4) pml[((size_t)jp * NN + g * LL + i0 + row) * 4 + h] = l;
    else         pml[(size_t)jp * NN + g * LL + i0 + row] = l;
  }
}

// ---------------- fused combine1 + GEMM2 (grid 128, 4 waves x 16 nodes) -----
__global__ __launch_bounds__(256) void k_gemm2c(
    const bf16* __restrict__ pacc, const float* __restrict__ pml1,
    const bf16* __restrict__ Wb2, const bf16* __restrict__ sm2,
    bf16* __restrict__ WfT, float* __restrict__ es, float* __restrict__ ed,
    uint32_t* __restrict__ edmax) {
  int t = threadIdx.x;
  int lane = t & 63, w = t >> 6;
  int quad = lane >> 4, c = lane & 15;
  int n0 = blockIdx.x * 64 + w * 16;
  int node = n0 + c;
  float4 l4 = make_float4(0.f, 0.f, 0.f, 0.f);
#pragma unroll
  for (int p = 0; p < 2; p++) {
    float4 v = *(const float4*)&pml1[((size_t)p * NN + node) * 4];
    l4.x += v.x; l4.y += v.y; l4.z += v.z; l4.w += v.w;
  }
  float linv[4] = {1.f / l4.x, 1.f / l4.y, 1.f / l4.z, 1.f / l4.w};
  short8 af[4];
#pragma unroll
  for (int ks = 0; ks < 4; ks++) {
    float a[8] = {0.f, 0.f, 0.f, 0.f, 0.f, 0.f, 0.f, 0.f};
#pragma unroll
    for (int p = 0; p < 2; p++) {
      short8 v = *(const short8*)&pacc[((size_t)p * NN + node) * CC + ks * 32 + quad * 8];
#pragma unroll
      for (int i = 0; i < 8; i++) {
        union { short s[2]; float f; } cv; cv.s[0] = 0; cv.s[1] = v[i];
        a[i] += cv.f;
      }
    }
#pragma unroll
    for (int i = 0; i < 8; i++) {
      float vv = a[i] * linv[ks];
      vv = (vv > 0.f) ? vv : (__expf(vv) - 1.f); // ELU
      af[ks][i] = f2bs(vv);
    }
  }
  gemm_core<1>(af, Wb2, sm2, sm2 + 128, WfT, es, ed, edmax, n0, lane);
}

// ---------------- combine layer2 + residual + LayerNorm ----------------
__global__ __launch_bounds__(256) void k_combine2(const bf16* __restrict__ pacc,
    const float* __restrict__ pml2, const void* __restrict__ feats,
    const void* __restrict__ gamma, const void* __restrict__ beta,
    void* __restrict__ outp) {
  const bool bf = is_bf16_wire(gamma);
  int t = threadIdx.x;
  int node = blockIdx.x * 4 + (t >> 6);
  int lane = t & 63;
  float l = 0.f, a0 = 0.f, a1 = 0.f;
#pragma unroll
  for (int p = 0; p < 2; p++) {
    l  += pml2[(size_t)p * NN + node];
    a0 += __bfloat162float(pacc[((size_t)p * NN + node) * CC + lane]);
    a1 += __bfloat162float(pacc[((size_t)p * NN + node) * CC + 64 + lane]);
  }
  float y0 = ldw(feats, (size_t)node * CC + lane, bf) + a0 / l;
  float y1 = ldw(feats, (size_t)node * CC + 64 + lane, bf) + a1 / l;
  float s = y0 + y1, s2 = y0 * y0 + y1 * y1;
#pragma unroll
  for (int mm = 32; mm >= 1; mm >>= 1) { s += __shfl_xor(s, mm); s2 += __shfl_xor(s2, mm); }
  float mu = s * (1.f / 128.f);
  float var = fmaxf(s2 * (1.f / 128.f) - mu * mu, 0.f);
  float rs = rsqrtf(var + 1e-5f);
  float o0 = (y0 - mu) * rs * ldw(gamma, lane, bf) + ldw(beta, lane, bf);
  float o1 = (y1 - mu) * rs * ldw(gamma, 64 + lane, bf) + ldw(beta, 64 + lane, bf);
  if (bf) {
    ((bf16*)outp)[(size_t)node * CC + lane]      = __float2bfloat16(o0);
    ((bf16*)outp)[(size_t)node * CC + 64 + lane] = __float2bfloat16(o1);
  } else {
    ((float*)outp)[(size_t)node * CC + lane]      = o0;
    ((float*)outp)[(size_t)node * CC + 64 + lane] = o1;
  }
}

extern "C" void kernel_launch(void* const* d_in, const int* in_sizes, int n_in,
                              void* d_out, int out_size, void* d_ws, size_t ws_size,
                              hipStream_t stream) {
  const void* feats = d_in[0];
  const int*  imgs  = (const int*)d_in[1];
  const void* W1    = d_in[3];
  const void* as1   = d_in[4];
  const void* ad1   = d_in[5];
  const void* W2    = d_in[6];
  const void* as2   = d_in[7];
  const void* ad2   = d_in[8];
  const void* gamma = d_in[9];
  const void* beta  = d_in[10];

  char* ws = (char*)d_ws;
  uint32_t* edmax1 = (uint32_t*)(ws + 0);                 // 128 B
  uint32_t* edmax2 = (uint32_t*)(ws + 1024);              // 128 B
  uint32_t* bits   = (uint32_t*)(ws + 9437184);           // 1 MB
  bf16*     xb     = (bf16*)(ws + 10485760);              // 2 MB canonical feats
  bf16*     Wb1    = (bf16*)(ws + 12582912);              // 32 KB
  bf16*     Wb2    = (bf16*)(ws + 12615680);              // 32 KB
  bf16*     sm     = (bf16*)(ws + 12648448);              // 1 KB as/ad x2
  bf16*     WfT    = (bf16*)(ws + 12652544);              // 2 MB fragment-tiled
  float*    es1    = (float*)(ws + 16846848);             // 128 KB
  float*    ed1    = (float*)(ws + 16977920);             // 128 KB
  float*    es2    = (float*)(ws + 17108992);             // 32 KB
  float*    ed2    = (float*)(ws + 17141760);             // 32 KB
  float*    pml    = (float*)(ws + 17174528);             // 256 KB (jp=2)
  bf16*     pacc   = (bf16*)(ws + 18223104);              // 4 MB (jp=2)

  hipMemsetAsync(ws, 0, 2048, stream);                    // edmax1+edmax2
  hipLaunchKernelGGL(k_front, dim3(576), dim3(256), 0, stream,
                     feats, W1, W2, as1, ad1, as2, ad2, gamma,
                     xb, Wb1, Wb2, sm, imgs, bits);
  hipLaunchKernelGGL(k_gemm1, dim3(128), dim3(256), 0, stream,
                     xb, Wb1, sm, WfT, es1, ed1, edmax1);
  hipLaunchKernelGGL((k_attn<4>), dim3(1024), dim3(256), 0, stream,
                     WfT, es1, ed1, bits, edmax1, pacc, pml);
  hipLaunchKernelGGL(k_gemm2c, dim3(128), dim3(256), 0, stream,
                     pacc, pml, Wb2, sm + 256, WfT, es2, ed2, edmax2);
  hipLaunchKernelGGL((k_attn<1>), dim3(1024), dim3(256), 0, stream,
                     WfT, es2, ed2, bits, edmax2, pacc, pml);
  hipLaunchKernelGGL(k_combine2, dim3(2048), dim3(256), 0, stream,
                     pacc, pml, feats, gamma, beta, d_out);
}

// Round 15
// 176.125 us; speedup vs baseline: 2.3948x; 2.3948x over previous
//
#include <hip/hip_runtime.h>
#include <hip/hip_bf16.h>
#include <stdint.h>

#define LL 1024
#define CC 128
#define NG 8            // B*S graphs
#define NN (NG*LL)      // 8192 nodes total
typedef __hip_bfloat16 bf16;
typedef __attribute__((ext_vector_type(8))) short short8;
typedef __attribute__((ext_vector_type(4))) short short4v;
typedef __attribute__((ext_vector_type(4))) float f32x4;

__device__ __forceinline__ bool is_bf16_wire(const void* gamma) {
  return *(const uint32_t*)gamma == 0x3F803F80u;
}
__device__ __forceinline__ float ldw(const void* p, size_t i, bool bf) {
  return bf ? __bfloat162float(((const bf16*)p)[i]) : ((const float*)p)[i];
}
__device__ __forceinline__ uint32_t encf(float f) {
  uint32_t b = __float_as_uint(f);
  return (b & 0x80000000u) ? ~b : (b | 0x80000000u);
}
__device__ __forceinline__ float decf(uint32_t u) {
  return (u & 0x80000000u) ? __uint_as_float(u & 0x7FFFFFFFu) : __uint_as_float(~u);
}
__device__ __forceinline__ short f2bs(float x) {   // RNE, matches cvt_pk_bf16
  uint32_t u = __float_as_uint(x);
  u += 0x7FFFu + ((u >> 16) & 1u);
  return (short)(u >> 16);
}
__device__ __forceinline__ void cvt8(const void* src, bf16* dst, int i8, bool bf) {
  if (bf) {
    ((uint4*)dst)[i8] = ((const uint4*)src)[i8];
  } else {
    const float4* f = (const float4*)src;
    float4 a = f[2 * i8], b = f[2 * i8 + 1];
    short8 pk;
    pk[0] = f2bs(a.x); pk[1] = f2bs(a.y); pk[2] = f2bs(a.z); pk[3] = f2bs(a.w);
    pk[4] = f2bs(b.x); pk[5] = f2bs(b.y); pk[6] = f2bs(b.z); pk[7] = f2bs(b.w);
    *(short8*)&((short*)dst)[i8 * 8] = pk;
  }
}

// WfTf fragment-native layout: elem(g,n,o) = g*131072 + (n>>2)*512 + o*4 + (n&3)

// ---------------- k_front: convert (blocks 0-511) + adj scatter (512-2559) --
// r15: reverted from r14's LDS-bitmask (288us: 8x work replication, 3% occ,
// latency-serial) to r13's byte-scatter (41us @3.5TB/s writeback). One tweak:
// g = rel&7 clusters each graph's 1MB adj region onto one XCD under round-
// robin dispatch -> fewer cross-XCD dirty lines (perf heuristic only).
__global__ __launch_bounds__(256) void k_front(
    const void* __restrict__ feats, const void* __restrict__ W1,
    const void* __restrict__ W2, const void* __restrict__ as1,
    const void* __restrict__ ad1, const void* __restrict__ as2,
    const void* __restrict__ ad2, const void* __restrict__ gamma,
    bf16* __restrict__ xb, bf16* __restrict__ Wb1, bf16* __restrict__ Wb2,
    bf16* __restrict__ sm, const int* __restrict__ img,
    uint8_t* __restrict__ adj) {
  int bid = blockIdx.x;
  if (bid < 512) {
    const bool bf = is_bf16_wire(gamma);
    int t = bid * 256 + threadIdx.x;             // < 131072
    cvt8(feats, xb, t, bf);
    if (t < 2048) {
      cvt8(W1, Wb1, t, bf);
    } else if (t < 4096) {
      cvt8(W2, Wb2, t - 2048, bf);
    } else if (t < 4160) {
      int j = t - 4096;
      const void* srcs[4] = {as1, ad1, as2, ad2};
      cvt8(srcs[j >> 4], sm + (j >> 4) * 128, j & 15, bf);
    }
  } else {
    int rel = bid - 512;                         // 0..2047
    int g = rel & 7;                             // XCD-clustered graph pick
    int p = (rel >> 3) * 256 + threadIdx.x;      // pixel within graph
    int y = p >> 8, x = p & 255;
    const int* im = img + g * 65536;
    uint8_t* A = adj + (size_t)g * (LL * LL);
    int a = im[p];
    if (a > 0) {
      int nxs[4] = {x + 1, x, x + 1, x - 1};
      int nys[4] = {y, y + 1, y + 1, y + 1};
#pragma unroll
      for (int d = 0; d < 4; d++) {
        int nx = nxs[d], ny = nys[d];
        if (nx < 0 || nx > 255 || ny > 255) continue;
        int b = im[ny * 256 + nx];
        if (b > 0 && b != a) {
          A[(size_t)(a - 1) * LL + (b - 1)] = 1;
          A[(size_t)(b - 1) * LL + (a - 1)] = 1;
        }
      }
    }
  }
}

// ---------------- shared MFMA-GEMM core (per-wave; 16 nodes x 128 o x 128 k)
template <int NH>
__device__ __forceinline__ void gemm_core(const short8 af[4],
    const bf16* __restrict__ Wb, const bf16* __restrict__ asb,
    const bf16* __restrict__ adb, bf16* __restrict__ WfT,
    float* __restrict__ es, float* __restrict__ ed,
    uint32_t* __restrict__ edmax, int n0, int lane) {
  int quad = lane >> 4, c = lane & 15;
  int g = n0 >> 10;
  f32x4 acc[8];
#pragma unroll
  for (int dt = 0; dt < 8; dt++) acc[dt] = (f32x4){0.f, 0.f, 0.f, 0.f};
#pragma unroll
  for (int ks = 0; ks < 4; ks++)
#pragma unroll
    for (int dt = 0; dt < 8; dt++) {
      short8 bfr = *(const short8*)&Wb[(size_t)(dt * 16 + c) * CC + ks * 32 + quad * 8];
      acc[dt] = __builtin_amdgcn_mfma_f32_16x16x32_bf16(af[ks], bfr, acc[dt], 0, 0, 0);
    }
  // WfTf store: nw4 = nloc/4 + quad, o = dt*16+c -> coalesced 8B chunks
  {
    int nw4 = ((n0 & 1023) >> 2) + quad;
    bf16* wdst = WfT + (size_t)g * 131072 + (size_t)nw4 * 512 + c * 4;
#pragma unroll
    for (int dt = 0; dt < 8; dt++) {
      short4v pk;
#pragma unroll
      for (int r = 0; r < 4; r++) pk[r] = f2bs(acc[dt][r]);
      *(short4v*)&wdst[dt * 64] = pk;
    }
  }
  float sv[NH][4], dv[NH][4];
#pragma unroll
  for (int h = 0; h < NH; h++)
#pragma unroll
    for (int r = 0; r < 4; r++) { sv[h][r] = 0.f; dv[h][r] = 0.f; }
#pragma unroll
  for (int dt = 0; dt < 8; dt++) {
    int o = dt * 16 + c;
    float a_s = __bfloat162float(asb[o]);
    float a_d = __bfloat162float(adb[o]);
    int h = (NH == 4) ? (dt >> 1) : 0;
#pragma unroll
    for (int r = 0; r < 4; r++) {
      sv[h][r] += acc[dt][r] * a_s;
      dv[h][r] += acc[dt][r] * a_d;
    }
  }
#pragma unroll
  for (int m = 1; m <= 8; m <<= 1)
#pragma unroll
    for (int h = 0; h < NH; h++)
#pragma unroll
      for (int r = 0; r < 4; r++) {
        sv[h][r] += __shfl_xor(sv[h][r], m);
        dv[h][r] += __shfl_xor(dv[h][r], m);
      }
  if (c == 0) {
#pragma unroll
    for (int r = 0; r < 4; r++) {
      int node = n0 + quad * 4 + r;
#pragma unroll
      for (int h = 0; h < NH; h++) {
        es[node * NH + h] = sv[h][r];
        ed[node * NH + h] = dv[h][r];
      }
    }
  }
  float mq[NH];
#pragma unroll
  for (int h = 0; h < NH; h++) {
    mq[h] = fmaxf(fmaxf(dv[h][0], dv[h][1]), fmaxf(dv[h][2], dv[h][3]));
    mq[h] = fmaxf(mq[h], __shfl_xor(mq[h], 16));
    mq[h] = fmaxf(mq[h], __shfl_xor(mq[h], 32));
  }
  if (lane == 0)
#pragma unroll
    for (int h = 0; h < NH; h++)
      atomicMax(&edmax[g * NH + h], encf(mq[h]));
}

// ---------------- k_mid: pack (blocks 0-1023) + gemm1 (1024-1151, 4-wave) ---
__global__ __launch_bounds__(256) void k_mid(
    const uint8_t* __restrict__ adj, uint32_t* __restrict__ bits,
    const bf16* __restrict__ xb, const bf16* __restrict__ Wb1,
    const bf16* __restrict__ sm, bf16* __restrict__ WfT,
    float* __restrict__ es, float* __restrict__ ed,
    uint32_t* __restrict__ edmax) {
  int bid = blockIdx.x, t = threadIdx.x;
  if (bid < 1024) {
    int id = bid * 256 + t;                      // < 262144
    const uint32_t* src = (const uint32_t*)(adj + (size_t)id * 32);
    uint32_t w = 0;
#pragma unroll
    for (int d = 0; d < 8; d++) {
      uint32_t v = src[d];
      uint32_t nib = (((v & 0x01010101u) * 0x01020408u) >> 24) & 0xFu;
      w |= nib << (4 * d);
    }
    int i = (id >> 5) & 1023, wd = id & 31;
    if ((i >> 5) == wd) w |= 1u << (i & 31);     // self-loop diagonal
    bits[id] = w;
  } else {
    int lane = t & 63, w = t >> 6;
    int quad = lane >> 4, c = lane & 15;
    int n0 = (bid - 1024) * 64 + w * 16;
    short8 af[4];
#pragma unroll
    for (int ks = 0; ks < 4; ks++)
      af[ks] = *(const short8*)&xb[(size_t)(n0 + c) * CC + ks * 32 + quad * 8];
    gemm_core<4>(af, Wb1, sm, sm + 128, WfT, es, ed, edmax, n0, lane);
  }
}

// ---------------- MFMA GAT aggregation: 16-row blocks, j-split waves --------
// grid 1024 = g(8) x rowtile(64: 16 rows) x jp(2: 512 j).
template <int NH>
__global__ __launch_bounds__(256) void k_attn(
    const bf16* __restrict__ WfT, const float* __restrict__ esb,
    const float* __restrict__ edb, const uint32_t* __restrict__ bits,
    const uint32_t* __restrict__ edmax, bf16* __restrict__ pacc,
    float* __restrict__ pml) {
  __shared__ __align__(16) float red[4224];      // 2 wave-accs / ob buffer
  __shared__ float eds[NH * 520];                // ed transposed [h][j-local]
  __shared__ float lred[4][16 * NH];
  int t = threadIdx.x;
  int lane = t & 63, w = t >> 6;
  int quad = lane >> 4, c = lane & 15;
  int bid = blockIdx.x;
  int jp = bid & 1, rt = (bid >> 1) & 63, g = bid >> 7;
  int i0 = rt * 16;
  int node = g * LL + i0 + c;
  int J0 = jp * 512 + w * 128;                   // wave's j base within graph
  for (int u = t; u < 512 * NH; u += 256) {
    int h = u >> 9, j = u & 511;
    eds[h * 520 + j] = edb[(size_t)(g * LL + jp * 512 + j) * NH + h];
  }
  const float LOG2E = 1.44269504f;
  float esv[NH], cmv[NH];
  if (NH == 4) {
    const float4 e4 = *(const float4*)&esb[(size_t)node * 4];
    esv[0] = e4.x; esv[1] = e4.y; esv[2] = e4.z; esv[3] = e4.w;
  } else {
    esv[0] = esb[node];
  }
#pragma unroll
  for (int h = 0; h < NH; h++) {
    float mx = decf(edmax[NH == 4 ? g * 4 + h : g]);
    float m = esv[h] + mx; m = fmaxf(m, 0.2f * m);   // safe row-max upper bound
    cmv[h] = -m * LOG2E;
  }
  uint4 mk = *(const uint4*)&bits[(size_t)node * 32 + jp * 16 + w * 4];
  const uint32_t mkw[4] = {mk.x, mk.y, mk.z, mk.w};
  f32x4 acc[8];
#pragma unroll
  for (int dt = 0; dt < 8; dt++) acc[dt] = (f32x4){0.f, 0.f, 0.f, 0.f};
  float lsum[NH];
#pragma unroll
  for (int h = 0; h < NH; h++) lsum[h] = 0.f;
  const bf16* wb = WfT + (size_t)g * 131072 + (size_t)J0 * 128 + quad * 1024 + c * 4;
  __syncthreads();

  union FB { uint2 u[2]; short8 s; };
#pragma unroll
  for (int jb = 0; jb < 4; jb++) {
    short8 frag[8];
#pragma unroll
    for (int dt = 0; dt < 8; dt++) {
      FB f;
      f.u[0] = *(const uint2*)&wb[jb * 4096 + dt * 64];
      f.u[1] = *(const uint2*)&wb[jb * 4096 + dt * 64 + 512];
      frag[dt] = f.s;
    }
    int base_wj = w * 128 + jb * 32 + quad * 8;  // local j within block window
    uint32_t mw = mkw[jb] >> (quad * 8);
    float mf[8];
#pragma unroll
    for (int i = 0; i < 8; i++) mf[i] = (float)((mw >> i) & 1u);
#pragma unroll
    for (int h = 0; h < NH; h++) {
      const float* ep = &eds[h * 520 + base_wj];
      float4 ea = *(const float4*)ep;
      float4 eb = *(const float4*)(ep + 4);
      float ev[8] = {ea.x, ea.y, ea.z, ea.w, eb.x, eb.y, eb.z, eb.w};
      float pr[8];
      float lac = 0.f;
#pragma unroll
      for (int i = 0; i < 8; i++) {
        float e = esv[h] + ev[i];
        e = fmaxf(e, 0.2f * e);                  // leaky_relu
        float p = exp2f(fmaf(e, LOG2E, cmv[h]));
        p *= mf[i];
        lac += p;
        pr[i] = p;
      }
      lsum[h] += lac;
      union { short8 s; uint32_t u[4]; } A;
#pragma unroll
      for (int k = 0; k < 4; k++) {
        __hip_bfloat162 q = __float22bfloat162_rn(make_float2(pr[2*k], pr[2*k+1]));
        A.u[k] = *reinterpret_cast<uint32_t*>(&q);
      }
#pragma unroll
      for (int d2 = 0; d2 < 8 / NH; d2++) {
        int dt = h * (8 / NH) + d2;
        acc[dt] = __builtin_amdgcn_mfma_f32_16x16x32_bf16(A.s, frag[dt], acc[dt], 0, 0, 0);
      }
    }
  }
  // l: quad-reduce, stash per-wave row sums
#pragma unroll
  for (int h = 0; h < NH; h++) {
    float v = lsum[h];
    v += __shfl_xor(v, 16);
    v += __shfl_xor(v, 32);
    lsum[h] = v;
  }
  if (quad == 0)
#pragma unroll
    for (int h = 0; h < NH; h++) lred[w][c * NH + h] = lsum[h];
  // ---- cross-wave acc reduction (f32, float4 conflict-free) ----
  if (w == 1)
#pragma unroll
    for (int dt = 0; dt < 8; dt++) *(f32x4*)&red[dt * 256 + lane * 4] = acc[dt];
  if (w == 3)
#pragma unroll
    for (int dt = 0; dt < 8; dt++) *(f32x4*)&red[2048 + dt * 256 + lane * 4] = acc[dt];
  __syncthreads();
  if (w == 0)
#pragma unroll
    for (int dt = 0; dt < 8; dt++) acc[dt] += *(const f32x4*)&red[dt * 256 + lane * 4];
  if (w == 2)
#pragma unroll
    for (int dt = 0; dt < 8; dt++) acc[dt] += *(const f32x4*)&red[2048 + dt * 256 + lane * 4];
  __syncthreads();
  if (w == 2)
#pragma unroll
    for (int dt = 0; dt < 8; dt++) *(f32x4*)&red[dt * 256 + lane * 4] = acc[dt];
  __syncthreads();
  if (w == 0) {
#pragma unroll
    for (int dt = 0; dt < 8; dt++) acc[dt] += *(const f32x4*)&red[dt * 256 + lane * 4];
    // write reduced block tile to ob region: [row][d] stride 132 (2-way free)
#pragma unroll
    for (int dt = 0; dt < 8; dt++)
#pragma unroll
      for (int r = 0; r < 4; r++)
        red[2048 + (quad * 4 + r) * 132 + dt * 16 + c] = acc[dt][r];
  }
  __syncthreads();
  // cooperative coalesced partial store (16 rows x 128 d bf16 = 4 KB/block)
  {
    int row = t >> 4, d0 = (t & 15) * 8;
    const float* src = &red[2048 + row * 132 + d0];
    short8 pk;
#pragma unroll
    for (int k = 0; k < 8; k++) pk[k] = f2bs(src[k]);
    *(short8*)&pacc[((size_t)jp * NN + g * LL + i0 + row) * CC + d0] = pk;
  }
  if (t < 16 * NH) {
    float l = lred[0][t] + lred[1][t] + lred[2][t] + lred[3][t];
    int row = (NH == 4) ? (t >> 2) : t;
    int h = (NH == 4) ? (t & 3) : 0;
    if (NH == 4) pml[((size_t)jp * NN + g * LL + i0 + row) * 4 + h] = l;
    else         pml[(size_t)jp * NN + g * LL + i0 + row] = l;
  }
}

// ---------------- fused combine1 + GEMM2 (grid 128, 4 waves x 16 nodes) -----
__global__ __launch_bounds__(256) void k_gemm2c(
    const bf16* __restrict__ pacc, const float* __restrict__ pml1,
    const bf16* __restrict__ Wb2, const bf16* __restrict__ sm2,
    bf16* __restrict__ WfT, float* __restrict__ es, float* __restrict__ ed,
    uint32_t* __restrict__ edmax) {
  int t = threadIdx.x;
  int lane = t & 63, w = t >> 6;
  int quad = lane >> 4, c = lane & 15;
  int n0 = blockIdx.x * 64 + w * 16;
  int node = n0 + c;
  float4 l4 = make_float4(0.f, 0.f, 0.f, 0.f);
#pragma unroll
  for (int p = 0; p < 2; p++) {
    float4 v = *(const float4*)&pml1[((size_t)p * NN + node) * 4];
    l4.x += v.x; l4.y += v.y; l4.z += v.z; l4.w += v.w;
  }
  float linv[4] = {1.f / l4.x, 1.f / l4.y, 1.f / l4.z, 1.f / l4.w};
  short8 af[4];
#pragma unroll
  for (int ks = 0; ks < 4; ks++) {
    float a[8] = {0.f, 0.f, 0.f, 0.f, 0.f, 0.f, 0.f, 0.f};
#pragma unroll
    for (int p = 0; p < 2; p++) {
      short8 v = *(const short8*)&pacc[((size_t)p * NN + node) * CC + ks * 32 + quad * 8];
#pragma unroll
      for (int i = 0; i < 8; i++) {
        union { short s[2]; float f; } cv; cv.s[0] = 0; cv.s[1] = v[i];
        a[i] += cv.f;
      }
    }
#pragma unroll
    for (int i = 0; i < 8; i++) {
      float vv = a[i] * linv[ks];
      vv = (vv > 0.f) ? vv : (__expf(vv) - 1.f); // ELU
      af[ks][i] = f2bs(vv);
    }
  }
  gemm_core<1>(af, Wb2, sm2, sm2 + 128, WfT, es, ed, edmax, n0, lane);
}

// ---------------- combine layer2 + residual + LayerNorm ----------------
__global__ __launch_bounds__(256) void k_combine2(const bf16* __restrict__ pacc,
    const float* __restrict__ pml2, const void* __restrict__ feats,
    const void* __restrict__ gamma, const void* __restrict__ beta,
    void* __restrict__ outp) {
  const bool bf = is_bf16_wire(gamma);
  int t = threadIdx.x;
  int node = blockIdx.x * 4 + (t >> 6);
  int lane = t & 63;
  float l = 0.f, a0 = 0.f, a1 = 0.f;
#pragma unroll
  for (int p = 0; p < 2; p++) {
    l  += pml2[(size_t)p * NN + node];
    a0 += __bfloat162float(pacc[((size_t)p * NN + node) * CC + lane]);
    a1 += __bfloat162float(pacc[((size_t)p * NN + node) * CC + 64 + lane]);
  }
  float y0 = ldw(feats, (size_t)node * CC + lane, bf) + a0 / l;
  float y1 = ldw(feats, (size_t)node * CC + 64 + lane, bf) + a1 / l;
  float s = y0 + y1, s2 = y0 * y0 + y1 * y1;
#pragma unroll
  for (int mm = 32; mm >= 1; mm >>= 1) { s += __shfl_xor(s, mm); s2 += __shfl_xor(s2, mm); }
  float mu = s * (1.f / 128.f);
  float var = fmaxf(s2 * (1.f / 128.f) - mu * mu, 0.f);
  float rs = rsqrtf(var + 1e-5f);
  float o0 = (y0 - mu) * rs * ldw(gamma, lane, bf) + ldw(beta, lane, bf);
  float o1 = (y1 - mu) * rs * ldw(gamma, 64 + lane, bf) + ldw(beta, 64 + lane, bf);
  if (bf) {
    ((bf16*)outp)[(size_t)node * CC + lane]      = __float2bfloat16(o0);
    ((bf16*)outp)[(size_t)node * CC + 64 + lane] = __float2bfloat16(o1);
  } else {
    ((float*)outp)[(size_t)node * CC + lane]      = o0;
    ((float*)outp)[(size_t)node * CC + 64 + lane] = o1;
  }
}

extern "C" void kernel_launch(void* const* d_in, const int* in_sizes, int n_in,
                              void* d_out, int out_size, void* d_ws, size_t ws_size,
                              hipStream_t stream) {
  const void* feats = d_in[0];
  const int*  imgs  = (const int*)d_in[1];
  const void* W1    = d_in[3];
  const void* as1   = d_in[4];
  const void* ad1   = d_in[5];
  const void* W2    = d_in[6];
  const void* as2   = d_in[7];
  const void* ad2   = d_in[8];
  const void* gamma = d_in[9];
  const void* beta  = d_in[10];

  char* ws = (char*)d_ws;
  uint8_t*  adj    = (uint8_t*)ws;                        // 8 MB byte matrix
  uint32_t* edmax1 = (uint32_t*)(ws + 8388608);           // 128 B
  uint32_t* edmax2 = (uint32_t*)(ws + 8389632);           // 128 B
  uint32_t* bits   = (uint32_t*)(ws + 9437184);           // 1 MB
  bf16*     xb     = (bf16*)(ws + 10485760);              // 2 MB canonical feats
  bf16*     Wb1    = (bf16*)(ws + 12582912);              // 32 KB
  bf16*     Wb2    = (bf16*)(ws + 12615680);              // 32 KB
  bf16*     sm     = (bf16*)(ws + 12648448);              // 1 KB as/ad x2
  bf16*     WfT    = (bf16*)(ws + 12652544);              // 2 MB fragment-tiled
  float*    es1    = (float*)(ws + 16846848);             // 128 KB
  float*    ed1    = (float*)(ws + 16977920);             // 128 KB
  float*    es2    = (float*)(ws + 17108992);             // 32 KB
  float*    ed2    = (float*)(ws + 17141760);             // 32 KB
  float*    pml    = (float*)(ws + 17174528);             // 256 KB (jp=2)
  bf16*     pacc   = (bf16*)(ws + 18223104);              // 4 MB (jp=2)

  hipMemsetAsync(adj, 0, 8388608, stream);                // adj bytes
  hipMemsetAsync(ws + 8388608, 0, 1049600 - 8192, stream);// edmax1+edmax2 region
  hipLaunchKernelGGL(k_front, dim3(2560), dim3(256), 0, stream,
                     feats, W1, W2, as1, ad1, as2, ad2, gamma,
                     xb, Wb1, Wb2, sm, imgs, adj);
  hipLaunchKernelGGL(k_mid, dim3(1152), dim3(256), 0, stream,
                     adj, bits, xb, Wb1, sm, WfT, es1, ed1, edmax1);
  hipLaunchKernelGGL((k_attn<4>), dim3(1024), dim3(256), 0, stream,
                     WfT, es1, ed1, bits, edmax1, pacc, pml);
  hipLaunchKernelGGL(k_gemm2c, dim3(128), dim3(256), 0, stream,
                     pacc, pml, Wb2, sm + 256, WfT, es2, ed2, edmax2);
  hipLaunchKernelGGL((k_attn<1>), dim3(1024), dim3(256), 0, stream,
                     WfT, es2, ed2, bits, edmax2, pacc, pml);
  hipLaunchKernelGGL(k_combine2, dim3(2048), dim3(256), 0, stream,
                     pacc, pml, feats, gamma, beta, d_out);
}